// Round 6
// baseline (283.714 us; speedup 1.0000x reference)
//
#include <hip/hip_runtime.h>
#include <cstdint>
#include <cstddef>

typedef __bf16 bf16;
typedef bf16 bf16x2 __attribute__((ext_vector_type(2)));
typedef bf16 bf16x4 __attribute__((ext_vector_type(4)));
typedef bf16 bf16x8 __attribute__((ext_vector_type(8)));
typedef float f32x4 __attribute__((ext_vector_type(4)));
typedef float f32x16 __attribute__((ext_vector_type(16)));

union B2F { float f; bf16x2 h; };

// async global->LDS, 16B per lane. LDS dest must equal wave-uniform base + lane*16.
__device__ __forceinline__ void gload_lds16(const bf16* g, bf16* l) {
    __builtin_amdgcn_global_load_lds(
        (__attribute__((address_space(1))) void*)(uintptr_t)(g),
        (__attribute__((address_space(3))) void*)(l),
        16, 0, 0);
}

// ---------------- fused fp32 -> bf16 convert (x, w_q_lin, w_out) ----------------
__global__ __launch_bounds__(256) void cvt3_kernel(const float* __restrict__ a,
                                                   bf16* __restrict__ oa, int na4,
                                                   const float* __restrict__ b,
                                                   bf16* __restrict__ ob, int nb4,
                                                   const float* __restrict__ c,
                                                   bf16* __restrict__ oc, int nc4) {
    int i = blockIdx.x * 256 + threadIdx.x;
    const float* in; bf16* out;
    if (i < na4) { in = a; out = oa; }
    else if (i < na4 + nb4) { in = b; out = ob; i -= na4; }
    else if (i < na4 + nb4 + nc4) { in = c; out = oc; i -= na4 + nb4; }
    else return;
    float4 v = ((const float4*)in)[i];
    bf16x4 o;
    o[0] = (bf16)v.x; o[1] = (bf16)v.y; o[2] = (bf16)v.z; o[3] = (bf16)v.w;
    *(bf16x4*)(out + (size_t)i * 4) = o;
}

// ---------------- rope cos/sin table: [w (1024)][j (32)] ----------------
__global__ __launch_bounds__(256) void rope_tab_kernel(float2* __restrict__ t) {
    int i = blockIdx.x * 256 + threadIdx.x;   // 0..32767
    int w = i >> 5, j = i & 31;
    float inv = exp2f(-(float)j * (13.287712379549449f / 32.0f));
    float a = (float)w * inv;
    t[i] = make_float2(cosf(a), sinf(a));
}

// ---------------- BT-GEMM: C(M,N) = A(M,K) * B(N,K)^T, M=N=K=1024 per slice ----
template <bool F32OUT>
__global__ void __launch_bounds__(256) gemm_bt(const bf16* __restrict__ A,
                                               const bf16* __restrict__ B,
                                               void* __restrict__ Cout) {
    __shared__ alignas(16) bf16 As[128 * 64];
    __shared__ alignas(16) bf16 Bs[128 * 64];
    const int tid = threadIdx.x, lane = tid & 63, wave = tid >> 6;
    const int l15 = lane & 15, quad = lane >> 4;
    const int s = blockIdx.z;
    const bf16* Ab = A + ((size_t)s << 20) + (size_t)blockIdx.y * 128 * 1024;
    const bf16* Bb = B + ((size_t)(s & 3) << 20) + (size_t)blockIdx.x * 128 * 1024;
    const int wm = (wave >> 1) * 64, wn = (wave & 1) * 64;

    const f32x4 fzero = {0.f, 0.f, 0.f, 0.f};
    f32x4 acc[4][4];
    for (int i = 0; i < 4; ++i)
        for (int j = 0; j < 4; ++j) acc[i][j] = fzero;

    const int sr = wave * 8 + (lane >> 3);
    const int sc = (lane & 7) * 8;

    for (int kt = 0; kt < 16; ++kt) {
        __syncthreads();
        for (int it = 0; it < 4; ++it) {
            int r = it * 32 + sr;
            gload_lds16(Ab + (size_t)r * 1024 + kt * 64 + sc, As + r * 64 + sc);
            gload_lds16(Bb + (size_t)r * 1024 + kt * 64 + sc, Bs + r * 64 + sc);
        }
        __syncthreads();
        for (int kk = 0; kk < 2; ++kk) {
            bf16x8 af[4], bfr[4];
            for (int i = 0; i < 4; ++i)
                af[i] = *(const bf16x8*)(As + (wm + i * 16 + l15) * 64 + kk * 32 + quad * 8);
            for (int j = 0; j < 4; ++j)
                bfr[j] = *(const bf16x8*)(Bs + (wn + j * 16 + l15) * 64 + kk * 32 + quad * 8);
            for (int i = 0; i < 4; ++i)
                for (int j = 0; j < 4; ++j)
                    acc[i][j] = __builtin_amdgcn_mfma_f32_16x16x32_bf16(af[i], bfr[j],
                                                                        acc[i][j], 0, 0, 0);
        }
    }
    size_t cbase = ((size_t)s << 20) + (size_t)blockIdx.y * 128 * 1024 + blockIdx.x * 128;
    for (int i = 0; i < 4; ++i)
        for (int j = 0; j < 4; ++j) {
            int m = wm + i * 16 + quad * 4;
            int n = wn + j * 16 + l15;
            for (int r = 0; r < 4; ++r) {
                float v = acc[i][j][r];
                if (F32OUT)
                    ((float*)Cout)[cbase + (size_t)(m + r) * 1024 + n] = v;
                else
                    ((bf16*)Cout)[cbase + (size_t)(m + r) * 1024 + n] = (bf16)v;
            }
        }
}

// ---------------- conv(1x3 along w) + bias, RoPE, emit fragment-layout Q/V ----
// in : Yb[s][h][w] bf16.
// out: Vhat[s][head][wchunk(128)][d(128)][8w]  (V, B-operand frag layout for PV)
//      Qhat[s][head][dchunk(16)][w(1024)][8d]  (roped Q=K, frag layout, PRE-SCALED
//           by sqrt(log2(e)/32) so attention exp is a bare exp2)
__global__ void __launch_bounds__(256) conv_rope_kernel(
    const bf16* __restrict__ Yb, const float* __restrict__ wconv,
    const float* __restrict__ bconv, bf16* __restrict__ Qhat,
    bf16* __restrict__ Vhat, const float2* __restrict__ rtab) {
    __shared__ float Pt[32][260];
    const int s = blockIdx.z, cch = s & 3;
    const int h0 = blockIdx.y * 32, w0 = blockIdx.x * 256;
    const bf16* Y = Yb + ((size_t)s << 20);
    const float k0 = wconv[cch * 3], k1 = wconv[cch * 3 + 1], k2 = wconv[cch * 3 + 2];
    const float bias = bconv[cch];
    const float SQS = 0.21233045f;   // sqrt(log2(e)/32): folds softmax scale into Q=K

    // phase 1: conv 8 consecutive w per thread (4 iters cover 32h x 256w tile)
    for (int it = 0; it < 4; ++it) {
        const int hh = threadIdx.x >> 3;
        const int wseg = (threadIdx.x & 7) + it * 8;   // 0..31
        const int h = h0 + hh, w = w0 + wseg * 8;
        const bf16* yrow = Y + ((size_t)h << 10);
        bf16x8 yv = *(const bf16x8*)(yrow + w);
        float yc[10];
        yc[0] = (w > 0) ? (float)yrow[w - 1] : 0.f;
        for (int i = 0; i < 8; ++i) yc[i + 1] = (float)yv[i];
        yc[9] = (w + 8 < 1024) ? (float)yrow[w + 8] : 0.f;
        bf16x8 pb;
        for (int i = 0; i < 8; ++i) {
            float p = fmaf(k0, yc[i], fmaf(k1, yc[i + 1], fmaf(k2, yc[i + 2], bias)));
            Pt[hh][wseg * 8 + i] = p;
            pb[i] = (bf16)p;
        }
        const int head = h >> 7, d = h & 127;
        *(bf16x8*)(Vhat + ((((size_t)s * 8 + head) * 128 + (w >> 3)) << 10) + d * 8) = pb;
    }
    __syncthreads();
    // phase 2: rope 8 consecutive d per thread at fixed w, write Qhat (scaled)
    {
        const int dcb = threadIdx.x >> 6;            // 0..3 (dchunk within tile)
        const int head = h0 >> 7;
        const int d0 = (h0 & 127) + dcb * 8;         // global d of chunk start
        const int hb0 = dcb * 8;
        for (int it = 0; it < 4; ++it) {
            const int wl = (threadIdx.x & 63) + it * 64;
            const int w = w0 + wl;
            float q[8];
            if (d0 < 64) {
                for (int j = 0; j < 8; j += 2) {
                    float2 cs = rtab[(w << 5) + ((d0 + j) >> 1)];
                    float a = Pt[hb0 + j][wl], b = Pt[hb0 + j + 1][wl];
                    q[j]     = fmaf(a, cs.x, -b * cs.y);
                    q[j + 1] = fmaf(b, cs.x,  a * cs.y);
                }
            } else {
                for (int j = 0; j < 8; ++j) q[j] = Pt[hb0 + j][wl];
            }
            bf16x8 qb;
            for (int j = 0; j < 8; ++j) qb[j] = (bf16)(q[j] * SQS);
            *(bf16x8*)(Qhat + ((((size_t)s * 8 + head) * 16 + (d0 >> 3)) << 13) +
                       (size_t)w * 8) = qb;
        }
    }
}

// ---------------- fused flash attention: barrier-free, direct-global frags ----
// grid 512 flat: sh = b&63, qtile = b>>6 (same-sh blocks -> same XCD L2).
// 2 blocks/CU, 4 waves, 32 q/wave. NO LDS / NO barriers in the K-loop:
// K and V fragments are loaded global->VGPR (Qhat/Vhat are frag-ordered), served
// by L1/XCD-L2; compiler pipelines loads across iterations (no vmcnt(0) drains).
// S^T = K(A,m=key) x Q(B,n=q); P A-frags built in-register via bf16x2 + shfl_xor(32).
// out: AO[s][h][w] bf16
__global__ void __launch_bounds__(256, 2) attn_kernel(const bf16* __restrict__ Qhat,
                                                      const bf16* __restrict__ Vhat,
                                                      bf16* __restrict__ AO) {
    __shared__ alignas(16) char smem[35328];   // epilogue only: Ot 34816 B + lsf 512 B
    const int tid = threadIdx.x, lane = tid & 63, wave = tid >> 6;
    const int l31 = lane & 31, h = lane >> 5;
    const int b = blockIdx.x;
    const int sh = b & 63, qtile = b >> 6;
    const int s = sh >> 3, head = sh & 7, q0 = qtile * 128;
    const bf16* Qg = Qhat + (size_t)sh * 131072;
    const bf16* Vg = Vhat + (size_t)sh * 131072;

    // Q B-frags: n=q (lane&31), k=d: dc = kstep*2 + h
    const int myq = q0 + wave * 32 + l31;
    bf16x8 qf[8];
    for (int ks8 = 0; ks8 < 8; ++ks8)
        qf[ks8] = *(const bf16x8*)(Qg + (size_t)(ks8 * 2 + h) * 8192 + (size_t)myq * 8);

    f32x16 Oacc[4];
    for (int nt = 0; nt < 4; ++nt)
        for (int e = 0; e < 16; ++e) Oacc[nt][e] = 0.f;
    float lsum = 0.f;

    for (int kt = 0; kt < 16; ++kt) {
        // ---- S^T = K * Q : K frags direct from global (coalesced dwordx4) ----
        f32x16 st[2];
        for (int e = 0; e < 16; ++e) { st[0][e] = 0.f; st[1][e] = 0.f; }
        for (int ks8 = 0; ks8 < 8; ++ks8) {
            const bf16* kb = Qg + (size_t)(ks8 * 2 + h) * 8192 + (size_t)(kt * 64) * 8;
            bf16x8 kf0 = *(const bf16x8*)(kb + (size_t)l31 * 8);
            bf16x8 kf1 = *(const bf16x8*)(kb + (size_t)(32 + l31) * 8);
            st[0] = __builtin_amdgcn_mfma_f32_32x32x16_bf16(kf0, qf[ks8], st[0], 0, 0, 0);
            st[1] = __builtin_amdgcn_mfma_f32_32x32x16_bf16(kf1, qf[ks8], st[1], 0, 0, 0);
        }

        // ---- exp (scale pre-folded into Q), pack to bf16x2, per-lane lsum ----
        float pk[2][8], pkx[2][8];
        float lacc = 0.f;
        for (int mt = 0; mt < 2; ++mt)
            for (int k = 0; k < 8; ++k) {
                float a = exp2f(st[mt][2 * k]);
                float c = exp2f(st[mt][2 * k + 1]);
                lacc += a + c;
                B2F u; u.h = bf16x2{(bf16)a, (bf16)c};
                pk[mt][k] = u.f;
            }
        lsum += lacc;
        for (int mt = 0; mt < 2; ++mt)
            for (int k = 0; k < 8; ++k) pkx[mt][k] = __shfl_xor(pk[mt][k], 32);

        // ---- O += P * V : V frags direct from global ----
        for (int ks = 0; ks < 4; ++ks) {
            const int bb = ks & 1, mt = ks >> 1;
            bf16x8 pf;
            float* pfF = (float*)&pf;
            pfF[0] = h ? pkx[mt][4 * bb + 2] : pk[mt][4 * bb + 0];
            pfF[1] = h ? pkx[mt][4 * bb + 3] : pk[mt][4 * bb + 1];
            pfF[2] = h ? pk[mt][4 * bb + 2] : pkx[mt][4 * bb + 0];
            pfF[3] = h ? pk[mt][4 * bb + 3] : pkx[mt][4 * bb + 1];
            const bf16* vb = Vg + (size_t)(kt * 8 + ks * 2 + h) * 1024;
            for (int nt = 0; nt < 4; ++nt) {
                bf16x8 vf = *(const bf16x8*)(vb + (size_t)(nt * 32 + l31) * 8);
                Oacc[nt] = __builtin_amdgcn_mfma_f32_32x32x16_bf16(pf, vf, Oacc[nt], 0, 0, 0);
            }
        }
    }

    // ---- rinv broadcast: lsum per-lane (q=l31), halves hold key-halves ----
    lsum += __shfl_xor(lsum, 32);
    float* lsf = (float*)(smem + 34816) + wave * 32;
    if (lane < 32) lsf[lane] = 1.0f / lsum;
    f32x4 rv[4];
    __builtin_amdgcn_s_waitcnt(0);        // own LDS write visible (wave-private slot)
    for (int rg = 0; rg < 4; ++rg)
        rv[rg] = *(const f32x4*)(lsf + 8 * rg + 4 * h);

    // ---- epilogue: normalize, transpose through LDS, coalesced store ----
    bf16* Ot = (bf16*)smem;               // [d(128)][q(128)] stride 136
    for (int nt = 0; nt < 4; ++nt) {
        int d = nt * 32 + l31;
        for (int rg = 0; rg < 4; ++rg) {
            int q = wave * 32 + 8 * rg + 4 * h;
            bf16x4 o4;
            for (int e = 0; e < 4; ++e)
                o4[e] = (bf16)(Oacc[nt][rg * 4 + e] * rv[rg][e]);
            *(bf16x4*)(Ot + d * 136 + q) = o4;
        }
    }
    __syncthreads();
    bf16* AOg = AO + ((size_t)s << 20);
    for (int it = 0; it < 8; ++it) {
        int d = it * 16 + (tid >> 4);
        int qc = (tid & 15) * 8;
        bf16x8 v = *(const bf16x8*)(Ot + d * 136 + qc);
        *(bf16x8*)(AOg + (size_t)(head * 128 + d) * 1024 + q0 + qc) = v;
    }
}

// ---------------- launch ----------------
extern "C" void kernel_launch(void* const* d_in, const int* in_sizes, int n_in,
                              void* d_out, int out_size, void* d_ws, size_t ws_size,
                              hipStream_t stream) {
    const float* x  = (const float*)d_in[0];
    const float* wq = (const float*)d_in[1];
    const float* wc = (const float*)d_in[2];
    const float* bc = (const float*)d_in[3];
    const float* wo = (const float*)d_in[4];
    float* out = (float*)d_out;

    char* ws = (char*)d_ws;
    bf16* xb   = (bf16*)ws;                      // 16 MiB (x bf16; later aliased as AO)
    bf16* wqb  = (bf16*)(ws + (16u << 20));      //  8 MiB
    bf16* wob  = (bf16*)(ws + (24u << 20));      //  8 MiB
    bf16* Yb   = (bf16*)(ws + (32u << 20));      // 16 MiB  proj output
    bf16* Qhat = (bf16*)(ws + (48u << 20));      // 16 MiB  roped Q=K, frag layout
    bf16* Vhat = (bf16*)(ws + (64u << 20));      // 16 MiB  V, frag layout
    float2* rtab = (float2*)(ws + (80u << 20));  // 256 KiB cos/sin table
    bf16* AO   = xb;                             // alias: x consumed after gemm1

    cvt3_kernel<<<16384, 256, 0, stream>>>(x, xb, 2097152, wq, wqb, 1048576,
                                           wo, wob, 1048576);
    rope_tab_kernel<<<128, 256, 0, stream>>>(rtab);

    gemm_bt<false><<<dim3(8, 8, 8), 256, 0, stream>>>(xb, wqb, Yb);
    conv_rope_kernel<<<dim3(4, 32, 8), 256, 0, stream>>>(Yb, wc, bc, Qhat, Vhat, rtab);
    attn_kernel<<<512, 256, 0, stream>>>(Qhat, Vhat, AO);
    gemm_bt<true><<<dim3(8, 8, 8), 256, 0, stream>>>(AO, wob, out);
}

// Round 7
// 223.443 us; speedup vs baseline: 1.2697x; 1.2697x over previous
//
#include <hip/hip_runtime.h>
#include <cstdint>
#include <cstddef>

typedef __bf16 bf16;
typedef bf16 bf16x2 __attribute__((ext_vector_type(2)));
typedef bf16 bf16x4 __attribute__((ext_vector_type(4)));
typedef bf16 bf16x8 __attribute__((ext_vector_type(8)));
typedef float f32x4 __attribute__((ext_vector_type(4)));
typedef float f32x16 __attribute__((ext_vector_type(16)));

union B2F { float f; bf16x2 h; };

// async global->LDS, 16B per lane. LDS dest must equal wave-uniform base + lane*16.
__device__ __forceinline__ void gload_lds16(const bf16* g, bf16* l) {
    __builtin_amdgcn_global_load_lds(
        (__attribute__((address_space(1))) void*)(uintptr_t)(g),
        (__attribute__((address_space(3))) void*)(l),
        16, 0, 0);
}

// ---------------- fused fp32 -> bf16 convert (x, w_q_lin, w_out) ----------------
__global__ __launch_bounds__(256) void cvt3_kernel(const float* __restrict__ a,
                                                   bf16* __restrict__ oa, int na4,
                                                   const float* __restrict__ b,
                                                   bf16* __restrict__ ob, int nb4,
                                                   const float* __restrict__ c,
                                                   bf16* __restrict__ oc, int nc4) {
    int i = blockIdx.x * 256 + threadIdx.x;
    const float* in; bf16* out;
    if (i < na4) { in = a; out = oa; }
    else if (i < na4 + nb4) { in = b; out = ob; i -= na4; }
    else if (i < na4 + nb4 + nc4) { in = c; out = oc; i -= na4 + nb4; }
    else return;
    float4 v = ((const float4*)in)[i];
    bf16x4 o;
    o[0] = (bf16)v.x; o[1] = (bf16)v.y; o[2] = (bf16)v.z; o[3] = (bf16)v.w;
    *(bf16x4*)(out + (size_t)i * 4) = o;
}

// ---------------- rope cos/sin table: [w (1024)][j (32)] ----------------
__global__ __launch_bounds__(256) void rope_tab_kernel(float2* __restrict__ t) {
    int i = blockIdx.x * 256 + threadIdx.x;   // 0..32767
    int w = i >> 5, j = i & 31;
    float inv = exp2f(-(float)j * (13.287712379549449f / 32.0f));
    float a = (float)w * inv;
    t[i] = make_float2(cosf(a), sinf(a));
}

// ---------------- BT-GEMM: C(M,N) = A(M,K) * B(N,K)^T, M=N=K=1024 per slice ----
// flat grid 512, XCD swizzle: mt = b&7 pins each m-tile's A-panel to one XCD's L2
// (consecutive blocks round-robin XCDs); nt fastest within XCD for B temporal reuse.
template <bool F32OUT>
__global__ void __launch_bounds__(256) gemm_bt(const bf16* __restrict__ A,
                                               const bf16* __restrict__ B,
                                               void* __restrict__ Cout) {
    __shared__ alignas(16) bf16 As[128 * 64];
    __shared__ alignas(16) bf16 Bs[128 * 64];
    const int tid = threadIdx.x, lane = tid & 63, wave = tid >> 6;
    const int l15 = lane & 15, quad = lane >> 4;
    const int b = blockIdx.x;
    const int mt = b & 7, nt = (b >> 3) & 7, s = b >> 6;
    const bf16* Ab = A + ((size_t)s << 20) + (size_t)mt * 128 * 1024;
    const bf16* Bb = B + ((size_t)(s & 3) << 20) + (size_t)nt * 128 * 1024;
    const int wm = (wave >> 1) * 64, wn = (wave & 1) * 64;

    const f32x4 fzero = {0.f, 0.f, 0.f, 0.f};
    f32x4 acc[4][4];
    for (int i = 0; i < 4; ++i)
        for (int j = 0; j < 4; ++j) acc[i][j] = fzero;

    const int sr = wave * 8 + (lane >> 3);
    const int sc = (lane & 7) * 8;

    for (int kt = 0; kt < 16; ++kt) {
        __syncthreads();
        for (int it = 0; it < 4; ++it) {
            int r = it * 32 + sr;
            gload_lds16(Ab + (size_t)r * 1024 + kt * 64 + sc, As + r * 64 + sc);
            gload_lds16(Bb + (size_t)r * 1024 + kt * 64 + sc, Bs + r * 64 + sc);
        }
        __syncthreads();
        for (int kk = 0; kk < 2; ++kk) {
            bf16x8 af[4], bfr[4];
            for (int i = 0; i < 4; ++i)
                af[i] = *(const bf16x8*)(As + (wm + i * 16 + l15) * 64 + kk * 32 + quad * 8);
            for (int j = 0; j < 4; ++j)
                bfr[j] = *(const bf16x8*)(Bs + (wn + j * 16 + l15) * 64 + kk * 32 + quad * 8);
            for (int i = 0; i < 4; ++i)
                for (int j = 0; j < 4; ++j)
                    acc[i][j] = __builtin_amdgcn_mfma_f32_16x16x32_bf16(af[i], bfr[j],
                                                                        acc[i][j], 0, 0, 0);
        }
    }
    size_t cbase = ((size_t)s << 20) + (size_t)mt * 128 * 1024 + (size_t)nt * 128;
    for (int i = 0; i < 4; ++i)
        for (int j = 0; j < 4; ++j) {
            int m = wm + i * 16 + quad * 4;
            int n = wn + j * 16 + l15;
            for (int r = 0; r < 4; ++r) {
                float v = acc[i][j][r];
                if (F32OUT)
                    ((float*)Cout)[cbase + (size_t)(m + r) * 1024 + n] = v;
                else
                    ((bf16*)Cout)[cbase + (size_t)(m + r) * 1024 + n] = (bf16)v;
            }
        }
}

// ---------------- conv(1x3 along w) + bias, RoPE, emit fragment-layout Q/V ----
// in : Yb[s][h][w] bf16.
// out: Vhat[s][head][wchunk(128)][d(128)][8w]  (V, B-operand frag layout for PV)
//      Qhat[s][head][dchunk(16)][w(1024)][8d]  (roped Q=K, frag layout, PRE-SCALED
//           by sqrt(log2(e)/32) so attention exp is a bare exp2)
__global__ void __launch_bounds__(256) conv_rope_kernel(
    const bf16* __restrict__ Yb, const float* __restrict__ wconv,
    const float* __restrict__ bconv, bf16* __restrict__ Qhat,
    bf16* __restrict__ Vhat, const float2* __restrict__ rtab) {
    __shared__ float Pt[32][260];
    const int s = blockIdx.z, cch = s & 3;
    const int h0 = blockIdx.y * 32, w0 = blockIdx.x * 256;
    const bf16* Y = Yb + ((size_t)s << 20);
    const float k0 = wconv[cch * 3], k1 = wconv[cch * 3 + 1], k2 = wconv[cch * 3 + 2];
    const float bias = bconv[cch];
    const float SQS = 0.21233045f;   // sqrt(log2(e)/32): folds softmax scale into Q=K

    // phase 1: conv 8 consecutive w per thread (4 iters cover 32h x 256w tile)
    for (int it = 0; it < 4; ++it) {
        const int hh = threadIdx.x >> 3;
        const int wseg = (threadIdx.x & 7) + it * 8;   // 0..31
        const int h = h0 + hh, w = w0 + wseg * 8;
        const bf16* yrow = Y + ((size_t)h << 10);
        bf16x8 yv = *(const bf16x8*)(yrow + w);
        float yc[10];
        yc[0] = (w > 0) ? (float)yrow[w - 1] : 0.f;
        for (int i = 0; i < 8; ++i) yc[i + 1] = (float)yv[i];
        yc[9] = (w + 8 < 1024) ? (float)yrow[w + 8] : 0.f;
        bf16x8 pb;
        for (int i = 0; i < 8; ++i) {
            float p = fmaf(k0, yc[i], fmaf(k1, yc[i + 1], fmaf(k2, yc[i + 2], bias)));
            Pt[hh][wseg * 8 + i] = p;
            pb[i] = (bf16)p;
        }
        const int head = h >> 7, d = h & 127;
        *(bf16x8*)(Vhat + ((((size_t)s * 8 + head) * 128 + (w >> 3)) << 10) + d * 8) = pb;
    }
    __syncthreads();
    // phase 2: rope 8 consecutive d per thread at fixed w, write Qhat (scaled)
    {
        const int dcb = threadIdx.x >> 6;            // 0..3 (dchunk within tile)
        const int head = h0 >> 7;
        const int d0 = (h0 & 127) + dcb * 8;         // global d of chunk start
        const int hb0 = dcb * 8;
        for (int it = 0; it < 4; ++it) {
            const int wl = (threadIdx.x & 63) + it * 64;
            const int w = w0 + wl;
            float q[8];
            if (d0 < 64) {
                for (int j = 0; j < 8; j += 2) {
                    float2 cs = rtab[(w << 5) + ((d0 + j) >> 1)];
                    float a = Pt[hb0 + j][wl], b = Pt[hb0 + j + 1][wl];
                    q[j]     = fmaf(a, cs.x, -b * cs.y);
                    q[j + 1] = fmaf(b, cs.x,  a * cs.y);
                }
            } else {
                for (int j = 0; j < 8; ++j) q[j] = Pt[hb0 + j][wl];
            }
            bf16x8 qb;
            for (int j = 0; j < 8; ++j) qb[j] = (bf16)(q[j] * SQS);
            *(bf16x8*)(Qhat + ((((size_t)s * 8 + head) * 16 + (d0 >> 3)) << 13) +
                       (size_t)w * 8) = qb;
        }
    }
}

// ---------------- fused flash attention: 32x32x16 MFMA, register P, dbuf ------
// (round-5 structure — best measured: 49.2 us; LDS staging is load-bearing,
//  direct-global frags regressed 2.3x in round 6.)
// grid 512 flat: sh = b&63, qtile = b>>6 (same-sh blocks -> same XCD L2).
// 2 blocks/CU, 4 waves, 32 q/wave. S^T = K(A) x Q(B); register-P via shfl_xor(32).
__global__ void __launch_bounds__(256, 2) attn_kernel(const bf16* __restrict__ Qhat,
                                                      const bf16* __restrict__ Vhat,
                                                      bf16* __restrict__ AO) {
    __shared__ alignas(16) char smem[66048];
    // buffers: buf b at smem + b*32768: Ks [16dc][64key][8] 16KB + Vs [8wc][128d][8] 16KB
    // lsf at smem + 65536: 4 waves x 32 floats
    const int tid = threadIdx.x, lane = tid & 63, wave = tid >> 6;
    const int l31 = lane & 31, h = lane >> 5;
    const int b = blockIdx.x;
    const int sh = b & 63, qtile = b >> 6;
    const int s = sh >> 3, head = sh & 7, q0 = qtile * 128;
    const bf16* Qg = Qhat + (size_t)sh * 131072;
    const bf16* Vg = Vhat + (size_t)sh * 131072;

    // Q B-frags straight from global: n=q (lane&31), k=d: dc = kstep*2 + h
    const int myq = q0 + wave * 32 + l31;
    bf16x8 qf[8];
    for (int ks8 = 0; ks8 < 8; ++ks8)
        qf[ks8] = *(const bf16x8*)(Qg + (size_t)(ks8 * 2 + h) * 8192 + (size_t)myq * 8);

    f32x16 Oacc[4];
    for (int nt = 0; nt < 4; ++nt)
        for (int e = 0; e < 16; ++e) Oacc[nt][e] = 0.f;
    float lsum = 0.f;

    auto stage = [&](int kt, int buf) {
        bf16* Ks = (bf16*)(smem + buf * 32768);
        bf16* Vs = Ks + 8192;
        for (int t = 0; t < 4; ++t) {
            int dc = wave * 4 + t;
            gload_lds16(Qg + (size_t)dc * 8192 + (size_t)(kt * 64 + lane) * 8,
                        Ks + (dc * 64 + lane) * 8);
            int wc = dc >> 1, half = dc & 1;
            gload_lds16(Vg + (size_t)(kt * 8 + wc) * 1024 + (size_t)(half * 64 + lane) * 8,
                        Vs + (wc * 128 + half * 64 + lane) * 8);
        }
    };

    stage(0, 0);
    for (int kt = 0; kt < 16; ++kt) {
        __syncthreads();                  // drains prefetch vmcnt + prev-iter reads
        if (kt < 15) stage(kt + 1, (kt + 1) & 1);
        bf16* Ks = (bf16*)(smem + (kt & 1) * 32768);
        bf16* Vs = Ks + 8192;

        // ---- S^T = K * Q : m-tiles key {0..31},{32..63}; k = d in 8 steps of 16
        f32x16 st[2];
        for (int e = 0; e < 16; ++e) { st[0][e] = 0.f; st[1][e] = 0.f; }
        for (int ks8 = 0; ks8 < 8; ++ks8) {
            bf16x8 kf0 = *(const bf16x8*)(Ks + ((ks8 * 2 + h) * 64 + l31) * 8);
            bf16x8 kf1 = *(const bf16x8*)(Ks + ((ks8 * 2 + h) * 64 + 32 + l31) * 8);
            st[0] = __builtin_amdgcn_mfma_f32_32x32x16_bf16(kf0, qf[ks8], st[0], 0, 0, 0);
            st[1] = __builtin_amdgcn_mfma_f32_32x32x16_bf16(kf1, qf[ks8], st[1], 0, 0, 0);
        }

        // ---- exp (scale pre-folded into Q), pack to bf16x2, per-lane lsum ----
        float pk[2][8], pkx[2][8];
        float lacc = 0.f;
        for (int mt = 0; mt < 2; ++mt)
            for (int k = 0; k < 8; ++k) {
                float a = exp2f(st[mt][2 * k]);
                float c = exp2f(st[mt][2 * k + 1]);
                lacc += a + c;
                B2F u; u.h = bf16x2{(bf16)a, (bf16)c};
                pk[mt][k] = u.f;
            }
        lsum += lacc;
        for (int mt = 0; mt < 2; ++mt)
            for (int k = 0; k < 8; ++k) pkx[mt][k] = __shfl_xor(pk[mt][k], 32);

        // ---- O += P * V : k = key in 4 steps of 16; P A-frag from pk/pkx ----
        for (int ks = 0; ks < 4; ++ks) {
            const int bb = ks & 1, mt = ks >> 1;
            bf16x8 pf;
            float* pfF = (float*)&pf;
            pfF[0] = h ? pkx[mt][4 * bb + 2] : pk[mt][4 * bb + 0];
            pfF[1] = h ? pkx[mt][4 * bb + 3] : pk[mt][4 * bb + 1];
            pfF[2] = h ? pk[mt][4 * bb + 2] : pkx[mt][4 * bb + 0];
            pfF[3] = h ? pk[mt][4 * bb + 3] : pkx[mt][4 * bb + 1];
            for (int nt = 0; nt < 4; ++nt) {
                bf16x8 vf = *(const bf16x8*)(Vs + ((ks * 2 + h) * 128 + nt * 32 + l31) * 8);
                Oacc[nt] = __builtin_amdgcn_mfma_f32_32x32x16_bf16(pf, vf, Oacc[nt], 0, 0, 0);
            }
        }
    }

    // ---- rinv broadcast: lsum is per-lane (q=l31), halves hold key-halves ----
    lsum += __shfl_xor(lsum, 32);
    float* lsf = (float*)(smem + 65536) + wave * 32;
    if (lane < 32) lsf[lane] = 1.0f / lsum;
    f32x4 rv[4];
    __builtin_amdgcn_s_waitcnt(0);        // own LDS write visible (wave-private slot)
    for (int rg = 0; rg < 4; ++rg)
        rv[rg] = *(const f32x4*)(lsf + 8 * rg + 4 * h);

    // ---- epilogue: normalize, transpose through LDS, coalesced store ----
    __syncthreads();
    bf16* Ot = (bf16*)smem;               // [d(128)][q(128)] stride 136
    for (int nt = 0; nt < 4; ++nt) {
        int d = nt * 32 + l31;
        for (int rg = 0; rg < 4; ++rg) {
            int q = wave * 32 + 8 * rg + 4 * h;
            bf16x4 o4;
            for (int e = 0; e < 4; ++e)
                o4[e] = (bf16)(Oacc[nt][rg * 4 + e] * rv[rg][e]);
            *(bf16x4*)(Ot + d * 136 + q) = o4;
        }
    }
    __syncthreads();
    bf16* AOg = AO + ((size_t)s << 20);
    for (int it = 0; it < 8; ++it) {
        int d = it * 16 + (tid >> 4);
        int qc = (tid & 15) * 8;
        bf16x8 v = *(const bf16x8*)(Ot + d * 136 + qc);
        *(bf16x8*)(AOg + (size_t)(head * 128 + d) * 1024 + q0 + qc) = v;
    }
}

// ---------------- launch ----------------
extern "C" void kernel_launch(void* const* d_in, const int* in_sizes, int n_in,
                              void* d_out, int out_size, void* d_ws, size_t ws_size,
                              hipStream_t stream) {
    const float* x  = (const float*)d_in[0];
    const float* wq = (const float*)d_in[1];
    const float* wc = (const float*)d_in[2];
    const float* bc = (const float*)d_in[3];
    const float* wo = (const float*)d_in[4];
    float* out = (float*)d_out;

    char* ws = (char*)d_ws;
    bf16* xb   = (bf16*)ws;                      // 16 MiB (x bf16; later aliased as AO)
    bf16* wqb  = (bf16*)(ws + (16u << 20));      //  8 MiB
    bf16* wob  = (bf16*)(ws + (24u << 20));      //  8 MiB
    bf16* Yb   = (bf16*)(ws + (32u << 20));      // 16 MiB  proj output
    bf16* Qhat = (bf16*)(ws + (48u << 20));      // 16 MiB  roped Q=K, frag layout
    bf16* Vhat = (bf16*)(ws + (64u << 20));      // 16 MiB  V, frag layout
    float2* rtab = (float2*)(ws + (80u << 20));  // 256 KiB cos/sin table
    bf16* AO   = xb;                             // alias: x consumed after gemm1

    cvt3_kernel<<<16384, 256, 0, stream>>>(x, xb, 2097152, wq, wqb, 1048576,
                                           wo, wob, 1048576);
    rope_tab_kernel<<<128, 256, 0, stream>>>(rtab);

    gemm_bt<false><<<512, 256, 0, stream>>>(xb, wqb, Yb);
    conv_rope_kernel<<<dim3(4, 32, 8), 256, 0, stream>>>(Yb, wc, bc, Qhat, Vhat, rtab);
    attn_kernel<<<512, 256, 0, stream>>>(Qhat, Vhat, AO);
    gemm_bt<true><<<512, 256, 0, stream>>>(AO, wob, out);
}

// Round 8
// 222.556 us; speedup vs baseline: 1.2748x; 1.0040x over previous
//
#include <hip/hip_runtime.h>
#include <cstdint>
#include <cstddef>

typedef __bf16 bf16;
typedef bf16 bf16x2 __attribute__((ext_vector_type(2)));
typedef bf16 bf16x4 __attribute__((ext_vector_type(4)));
typedef bf16 bf16x8 __attribute__((ext_vector_type(8)));
typedef float f32x4 __attribute__((ext_vector_type(4)));
typedef float f32x16 __attribute__((ext_vector_type(16)));

union B2F { float f; bf16x2 h; };

// async global->LDS, 16B per lane. LDS dest must equal wave-uniform base + lane*16.
__device__ __forceinline__ void gload_lds16(const bf16* g, bf16* l) {
    __builtin_amdgcn_global_load_lds(
        (__attribute__((address_space(1))) void*)(uintptr_t)(g),
        (__attribute__((address_space(3))) void*)(l),
        16, 0, 0);
}

// ---------------- fused fp32 -> bf16 convert (x, w_q_lin, w_out) ----------------
__global__ __launch_bounds__(256) void cvt3_kernel(const float* __restrict__ a,
                                                   bf16* __restrict__ oa, int na4,
                                                   const float* __restrict__ b,
                                                   bf16* __restrict__ ob, int nb4,
                                                   const float* __restrict__ c,
                                                   bf16* __restrict__ oc, int nc4) {
    int i = blockIdx.x * 256 + threadIdx.x;
    const float* in; bf16* out;
    if (i < na4) { in = a; out = oa; }
    else if (i < na4 + nb4) { in = b; out = ob; i -= na4; }
    else if (i < na4 + nb4 + nc4) { in = c; out = oc; i -= na4 + nb4; }
    else return;
    float4 v = ((const float4*)in)[i];
    bf16x4 o;
    o[0] = (bf16)v.x; o[1] = (bf16)v.y; o[2] = (bf16)v.z; o[3] = (bf16)v.w;
    *(bf16x4*)(out + (size_t)i * 4) = o;
}

// ---------------- rope cos/sin table: [w (1024)][j (32)] ----------------
__global__ __launch_bounds__(256) void rope_tab_kernel(float2* __restrict__ t) {
    int i = blockIdx.x * 256 + threadIdx.x;   // 0..32767
    int w = i >> 5, j = i & 31;
    float inv = exp2f(-(float)j * (13.287712379549449f / 32.0f));
    float a = (float)w * inv;
    t[i] = make_float2(cosf(a), sinf(a));
}

// ---------------- BT-GEMM: C(M,N) = A(M,K) * B(N,K)^T, M=N=K=1024 per slice ----
// flat grid 512, slice-per-XCD: s = b&7 -> XCD (b%8) holds ALL 64 blocks of one
// slice (2 blocks/CU x 32 CU). Per-XCD working set = A-panel 2MB + B-panel 2MB
// = 4MB = L2 size, so A/B are HBM-fetched once and L2-served 8x each.
template <bool F32OUT>
__global__ void __launch_bounds__(256) gemm_bt(const bf16* __restrict__ A,
                                               const bf16* __restrict__ B,
                                               void* __restrict__ Cout) {
    __shared__ alignas(16) bf16 As[128 * 64];
    __shared__ alignas(16) bf16 Bs[128 * 64];
    const int tid = threadIdx.x, lane = tid & 63, wave = tid >> 6;
    const int l15 = lane & 15, quad = lane >> 4;
    const int b = blockIdx.x;
    const int s = b & 7, mt = (b >> 3) & 7, nt = b >> 6;
    const bf16* Ab = A + ((size_t)s << 20) + (size_t)mt * 128 * 1024;
    const bf16* Bb = B + ((size_t)(s & 3) << 20) + (size_t)nt * 128 * 1024;
    const int wm = (wave >> 1) * 64, wn = (wave & 1) * 64;

    const f32x4 fzero = {0.f, 0.f, 0.f, 0.f};
    f32x4 acc[4][4];
    for (int i = 0; i < 4; ++i)
        for (int j = 0; j < 4; ++j) acc[i][j] = fzero;

    const int sr = wave * 8 + (lane >> 3);
    const int sc = (lane & 7) * 8;

    for (int kt = 0; kt < 16; ++kt) {
        __syncthreads();
        for (int it = 0; it < 4; ++it) {
            int r = it * 32 + sr;
            gload_lds16(Ab + (size_t)r * 1024 + kt * 64 + sc, As + r * 64 + sc);
            gload_lds16(Bb + (size_t)r * 1024 + kt * 64 + sc, Bs + r * 64 + sc);
        }
        __syncthreads();
        for (int kk = 0; kk < 2; ++kk) {
            bf16x8 af[4], bfr[4];
            for (int i = 0; i < 4; ++i)
                af[i] = *(const bf16x8*)(As + (wm + i * 16 + l15) * 64 + kk * 32 + quad * 8);
            for (int j = 0; j < 4; ++j)
                bfr[j] = *(const bf16x8*)(Bs + (wn + j * 16 + l15) * 64 + kk * 32 + quad * 8);
            for (int i = 0; i < 4; ++i)
                for (int j = 0; j < 4; ++j)
                    acc[i][j] = __builtin_amdgcn_mfma_f32_16x16x32_bf16(af[i], bfr[j],
                                                                        acc[i][j], 0, 0, 0);
        }
    }
    size_t cbase = ((size_t)s << 20) + (size_t)mt * 128 * 1024 + (size_t)nt * 128;
    for (int i = 0; i < 4; ++i)
        for (int j = 0; j < 4; ++j) {
            int m = wm + i * 16 + quad * 4;
            int n = wn + j * 16 + l15;
            for (int r = 0; r < 4; ++r) {
                float v = acc[i][j][r];
                if (F32OUT)
                    ((float*)Cout)[cbase + (size_t)(m + r) * 1024 + n] = v;
                else
                    ((bf16*)Cout)[cbase + (size_t)(m + r) * 1024 + n] = (bf16)v;
            }
        }
}

// ---------------- conv(1x3 along w) + bias, RoPE, emit fragment-layout Q/V ----
// in : Yb[s][h][w] bf16.
// out: Vhat[s][head][wchunk(128)][d(128)][8w]  (V, B-operand frag layout for PV)
//      Qhat[s][head][dchunk(16)][w(1024)][8d]  (roped Q=K, frag layout, PRE-SCALED
//           by sqrt(log2(e)/32) so attention exp is a bare exp2)
__global__ void __launch_bounds__(256) conv_rope_kernel(
    const bf16* __restrict__ Yb, const float* __restrict__ wconv,
    const float* __restrict__ bconv, bf16* __restrict__ Qhat,
    bf16* __restrict__ Vhat, const float2* __restrict__ rtab) {
    __shared__ float Pt[32][260];
    const int s = blockIdx.z, cch = s & 3;
    const int h0 = blockIdx.y * 32, w0 = blockIdx.x * 256;
    const bf16* Y = Yb + ((size_t)s << 20);
    const float k0 = wconv[cch * 3], k1 = wconv[cch * 3 + 1], k2 = wconv[cch * 3 + 2];
    const float bias = bconv[cch];
    const float SQS = 0.21233045f;   // sqrt(log2(e)/32): folds softmax scale into Q=K

    // phase 1: conv 8 consecutive w per thread (4 iters cover 32h x 256w tile)
    for (int it = 0; it < 4; ++it) {
        const int hh = threadIdx.x >> 3;
        const int wseg = (threadIdx.x & 7) + it * 8;   // 0..31
        const int h = h0 + hh, w = w0 + wseg * 8;
        const bf16* yrow = Y + ((size_t)h << 10);
        bf16x8 yv = *(const bf16x8*)(yrow + w);
        float yc[10];
        yc[0] = (w > 0) ? (float)yrow[w - 1] : 0.f;
        for (int i = 0; i < 8; ++i) yc[i + 1] = (float)yv[i];
        yc[9] = (w + 8 < 1024) ? (float)yrow[w + 8] : 0.f;
        bf16x8 pb;
        for (int i = 0; i < 8; ++i) {
            float p = fmaf(k0, yc[i], fmaf(k1, yc[i + 1], fmaf(k2, yc[i + 2], bias)));
            Pt[hh][wseg * 8 + i] = p;
            pb[i] = (bf16)p;
        }
        const int head = h >> 7, d = h & 127;
        *(bf16x8*)(Vhat + ((((size_t)s * 8 + head) * 128 + (w >> 3)) << 10) + d * 8) = pb;
    }
    __syncthreads();
    // phase 2: rope 8 consecutive d per thread at fixed w, write Qhat (scaled)
    {
        const int dcb = threadIdx.x >> 6;            // 0..3 (dchunk within tile)
        const int head = h0 >> 7;
        const int d0 = (h0 & 127) + dcb * 8;         // global d of chunk start
        const int hb0 = dcb * 8;
        for (int it = 0; it < 4; ++it) {
            const int wl = (threadIdx.x & 63) + it * 64;
            const int w = w0 + wl;
            float q[8];
            if (d0 < 64) {
                for (int j = 0; j < 8; j += 2) {
                    float2 cs = rtab[(w << 5) + ((d0 + j) >> 1)];
                    float a = Pt[hb0 + j][wl], b = Pt[hb0 + j + 1][wl];
                    q[j]     = fmaf(a, cs.x, -b * cs.y);
                    q[j + 1] = fmaf(b, cs.x,  a * cs.y);
                }
            } else {
                for (int j = 0; j < 8; ++j) q[j] = Pt[hb0 + j][wl];
            }
            bf16x8 qb;
            for (int j = 0; j < 8; ++j) qb[j] = (bf16)(q[j] * SQS);
            *(bf16x8*)(Qhat + ((((size_t)s * 8 + head) * 16 + (d0 >> 3)) << 13) +
                       (size_t)w * 8) = qb;
        }
    }
}

// ---------------- fused flash attention: 32x32x16 MFMA, register P, dbuf ------
// grid 512 flat: sh = b&63, qtile = b>>6 (same-sh blocks -> same XCD L2).
// 2 blocks/CU, 4 waves, 32 q/wave. S^T = K(A) x Q(B); register-P via shfl_xor(32).
__global__ void __launch_bounds__(256, 2) attn_kernel(const bf16* __restrict__ Qhat,
                                                      const bf16* __restrict__ Vhat,
                                                      bf16* __restrict__ AO) {
    __shared__ alignas(16) char smem[66048];
    // buffers: buf b at smem + b*32768: Ks [16dc][64key][8] 16KB + Vs [8wc][128d][8] 16KB
    // lsf at smem + 65536: 4 waves x 32 floats
    const int tid = threadIdx.x, lane = tid & 63, wave = tid >> 6;
    const int l31 = lane & 31, h = lane >> 5;
    const int b = blockIdx.x;
    const int sh = b & 63, qtile = b >> 6;
    const int s = sh >> 3, head = sh & 7, q0 = qtile * 128;
    const bf16* Qg = Qhat + (size_t)sh * 131072;
    const bf16* Vg = Vhat + (size_t)sh * 131072;

    // Q B-frags straight from global: n=q (lane&31), k=d: dc = kstep*2 + h
    const int myq = q0 + wave * 32 + l31;
    bf16x8 qf[8];
    for (int ks8 = 0; ks8 < 8; ++ks8)
        qf[ks8] = *(const bf16x8*)(Qg + (size_t)(ks8 * 2 + h) * 8192 + (size_t)myq * 8);

    f32x16 Oacc[4];
    for (int nt = 0; nt < 4; ++nt)
        for (int e = 0; e < 16; ++e) Oacc[nt][e] = 0.f;
    float lsum = 0.f;

    auto stage = [&](int kt, int buf) {
        bf16* Ks = (bf16*)(smem + buf * 32768);
        bf16* Vs = Ks + 8192;
        for (int t = 0; t < 4; ++t) {
            int dc = wave * 4 + t;
            gload_lds16(Qg + (size_t)dc * 8192 + (size_t)(kt * 64 + lane) * 8,
                        Ks + (dc * 64 + lane) * 8);
            int wc = dc >> 1, half = dc & 1;
            gload_lds16(Vg + (size_t)(kt * 8 + wc) * 1024 + (size_t)(half * 64 + lane) * 8,
                        Vs + (wc * 128 + half * 64 + lane) * 8);
        }
    };

    stage(0, 0);
    for (int kt = 0; kt < 16; ++kt) {
        __syncthreads();                  // drains prefetch vmcnt + prev-iter reads
        if (kt < 15) stage(kt + 1, (kt + 1) & 1);
        bf16* Ks = (bf16*)(smem + (kt & 1) * 32768);
        bf16* Vs = Ks + 8192;

        // ---- S^T = K * Q : m-tiles key {0..31},{32..63}; k = d in 8 steps of 16
        f32x16 st[2];
        for (int e = 0; e < 16; ++e) { st[0][e] = 0.f; st[1][e] = 0.f; }
        for (int ks8 = 0; ks8 < 8; ++ks8) {
            bf16x8 kf0 = *(const bf16x8*)(Ks + ((ks8 * 2 + h) * 64 + l31) * 8);
            bf16x8 kf1 = *(const bf16x8*)(Ks + ((ks8 * 2 + h) * 64 + 32 + l31) * 8);
            st[0] = __builtin_amdgcn_mfma_f32_32x32x16_bf16(kf0, qf[ks8], st[0], 0, 0, 0);
            st[1] = __builtin_amdgcn_mfma_f32_32x32x16_bf16(kf1, qf[ks8], st[1], 0, 0, 0);
        }

        // ---- exp (scale pre-folded into Q), pack to bf16x2, per-lane lsum ----
        float pk[2][8], pkx[2][8];
        float lacc = 0.f;
        for (int mt = 0; mt < 2; ++mt)
            for (int k = 0; k < 8; ++k) {
                float a = exp2f(st[mt][2 * k]);
                float c = exp2f(st[mt][2 * k + 1]);
                lacc += a + c;
                B2F u; u.h = bf16x2{(bf16)a, (bf16)c};
                pk[mt][k] = u.f;
            }
        lsum += lacc;
        for (int mt = 0; mt < 2; ++mt)
            for (int k = 0; k < 8; ++k) pkx[mt][k] = __shfl_xor(pk[mt][k], 32);

        // ---- O += P * V : k = key in 4 steps of 16; P A-frag from pk/pkx ----
        for (int ks = 0; ks < 4; ++ks) {
            const int bb = ks & 1, mt = ks >> 1;
            bf16x8 pf;
            float* pfF = (float*)&pf;
            pfF[0] = h ? pkx[mt][4 * bb + 2] : pk[mt][4 * bb + 0];
            pfF[1] = h ? pkx[mt][4 * bb + 3] : pk[mt][4 * bb + 1];
            pfF[2] = h ? pk[mt][4 * bb + 2] : pkx[mt][4 * bb + 0];
            pfF[3] = h ? pk[mt][4 * bb + 3] : pkx[mt][4 * bb + 1];
            for (int nt = 0; nt < 4; ++nt) {
                bf16x8 vf = *(const bf16x8*)(Vs + ((ks * 2 + h) * 128 + nt * 32 + l31) * 8);
                Oacc[nt] = __builtin_amdgcn_mfma_f32_32x32x16_bf16(pf, vf, Oacc[nt], 0, 0, 0);
            }
        }
    }

    // ---- rinv broadcast: lsum is per-lane (q=l31), halves hold key-halves ----
    lsum += __shfl_xor(lsum, 32);
    float* lsf = (float*)(smem + 65536) + wave * 32;
    if (lane < 32) lsf[lane] = 1.0f / lsum;
    f32x4 rv[4];
    __builtin_amdgcn_s_waitcnt(0);        // own LDS write visible (wave-private slot)
    for (int rg = 0; rg < 4; ++rg)
        rv[rg] = *(const f32x4*)(lsf + 8 * rg + 4 * h);

    // ---- epilogue: normalize, transpose through LDS, coalesced store ----
    __syncthreads();
    bf16* Ot = (bf16*)smem;               // [d(128)][q(128)] stride 136
    for (int nt = 0; nt < 4; ++nt) {
        int d = nt * 32 + l31;
        for (int rg = 0; rg < 4; ++rg) {
            int q = wave * 32 + 8 * rg + 4 * h;
            bf16x4 o4;
            for (int e = 0; e < 4; ++e)
                o4[e] = (bf16)(Oacc[nt][rg * 4 + e] * rv[rg][e]);
            *(bf16x4*)(Ot + d * 136 + q) = o4;
        }
    }
    __syncthreads();
    bf16* AOg = AO + ((size_t)s << 20);
    for (int it = 0; it < 8; ++it) {
        int d = it * 16 + (tid >> 4);
        int qc = (tid & 15) * 8;
        bf16x8 v = *(const bf16x8*)(Ot + d * 136 + qc);
        *(bf16x8*)(AOg + (size_t)(head * 128 + d) * 1024 + q0 + qc) = v;
    }
}

// ---------------- launch ----------------
extern "C" void kernel_launch(void* const* d_in, const int* in_sizes, int n_in,
                              void* d_out, int out_size, void* d_ws, size_t ws_size,
                              hipStream_t stream) {
    const float* x  = (const float*)d_in[0];
    const float* wq = (const float*)d_in[1];
    const float* wc = (const float*)d_in[2];
    const float* bc = (const float*)d_in[3];
    const float* wo = (const float*)d_in[4];
    float* out = (float*)d_out;

    char* ws = (char*)d_ws;
    bf16* xb   = (bf16*)ws;                      // 16 MiB (x bf16; later aliased as AO)
    bf16* wqb  = (bf16*)(ws + (16u << 20));      //  8 MiB
    bf16* wob  = (bf16*)(ws + (24u << 20));      //  8 MiB
    bf16* Yb   = (bf16*)(ws + (32u << 20));      // 16 MiB  proj output
    bf16* Qhat = (bf16*)(ws + (48u << 20));      // 16 MiB  roped Q=K, frag layout
    bf16* Vhat = (bf16*)(ws + (64u << 20));      // 16 MiB  V, frag layout
    float2* rtab = (float2*)(ws + (80u << 20));  // 256 KiB cos/sin table
    bf16* AO   = xb;                             // alias: x consumed after gemm1

    cvt3_kernel<<<16384, 256, 0, stream>>>(x, xb, 2097152, wq, wqb, 1048576,
                                           wo, wob, 1048576);
    rope_tab_kernel<<<128, 256, 0, stream>>>(rtab);

    gemm_bt<false><<<512, 256, 0, stream>>>(xb, wqb, Yb);
    conv_rope_kernel<<<dim3(4, 32, 8), 256, 0, stream>>>(Yb, wc, bc, Qhat, Vhat, rtab);
    attn_kernel<<<512, 256, 0, stream>>>(Qhat, Vhat, AO);
    gemm_bt<true><<<512, 256, 0, stream>>>(AO, wob, out);
}

// Round 9
// 220.865 us; speedup vs baseline: 1.2846x; 1.0077x over previous
//
#include <hip/hip_runtime.h>
#include <cstdint>
#include <cstddef>

typedef __bf16 bf16;
typedef bf16 bf16x2 __attribute__((ext_vector_type(2)));
typedef bf16 bf16x4 __attribute__((ext_vector_type(4)));
typedef bf16 bf16x8 __attribute__((ext_vector_type(8)));
typedef float f32x4 __attribute__((ext_vector_type(4)));
typedef float f32x16 __attribute__((ext_vector_type(16)));

// async global->LDS, 16B per lane. LDS dest must equal wave-uniform base + lane*16.
__device__ __forceinline__ void gload_lds16(const bf16* g, bf16* l) {
    __builtin_amdgcn_global_load_lds(
        (__attribute__((address_space(1))) void*)(uintptr_t)(g),
        (__attribute__((address_space(3))) void*)(l),
        16, 0, 0);
}

// ---------------- fused fp32 -> bf16 convert (x, w_q_lin, w_out) ----------------
__global__ __launch_bounds__(256) void cvt3_kernel(const float* __restrict__ a,
                                                   bf16* __restrict__ oa, int na4,
                                                   const float* __restrict__ b,
                                                   bf16* __restrict__ ob, int nb4,
                                                   const float* __restrict__ c,
                                                   bf16* __restrict__ oc, int nc4) {
    int i = blockIdx.x * 256 + threadIdx.x;
    const float* in; bf16* out;
    if (i < na4) { in = a; out = oa; }
    else if (i < na4 + nb4) { in = b; out = ob; i -= na4; }
    else if (i < na4 + nb4 + nc4) { in = c; out = oc; i -= na4 + nb4; }
    else return;
    float4 v = ((const float4*)in)[i];
    bf16x4 o;
    o[0] = (bf16)v.x; o[1] = (bf16)v.y; o[2] = (bf16)v.z; o[3] = (bf16)v.w;
    *(bf16x4*)(out + (size_t)i * 4) = o;
}

// ---------------- rope cos/sin table: [w (1024)][j (32)] ----------------
__global__ __launch_bounds__(256) void rope_tab_kernel(float2* __restrict__ t) {
    int i = blockIdx.x * 256 + threadIdx.x;   // 0..32767
    int w = i >> 5, j = i & 31;
    float inv = exp2f(-(float)j * (13.287712379549449f / 32.0f));
    float a = (float)w * inv;
    t[i] = make_float2(cosf(a), sinf(a));
}

// ---------------- BT-GEMM: C(M,N) = A(M,K) * B(N,K)^T, M=N=K=1024 per slice ----
template <bool F32OUT>
__global__ void __launch_bounds__(256) gemm_bt(const bf16* __restrict__ A,
                                               const bf16* __restrict__ B,
                                               void* __restrict__ Cout) {
    __shared__ alignas(16) bf16 As[128 * 64];
    __shared__ alignas(16) bf16 Bs[128 * 64];
    const int tid = threadIdx.x, lane = tid & 63, wave = tid >> 6;
    const int l15 = lane & 15, quad = lane >> 4;
    const int b = blockIdx.x;
    const int s = b & 7, mt = (b >> 3) & 7, nt = b >> 6;
    const bf16* Ab = A + ((size_t)s << 20) + (size_t)mt * 128 * 1024;
    const bf16* Bb = B + ((size_t)(s & 3) << 20) + (size_t)nt * 128 * 1024;
    const int wm = (wave >> 1) * 64, wn = (wave & 1) * 64;

    const f32x4 fzero = {0.f, 0.f, 0.f, 0.f};
    f32x4 acc[4][4];
    for (int i = 0; i < 4; ++i)
        for (int j = 0; j < 4; ++j) acc[i][j] = fzero;

    const int sr = wave * 8 + (lane >> 3);
    const int sc = (lane & 7) * 8;

    for (int kt = 0; kt < 16; ++kt) {
        __syncthreads();
        for (int it = 0; it < 4; ++it) {
            int r = it * 32 + sr;
            gload_lds16(Ab + (size_t)r * 1024 + kt * 64 + sc, As + r * 64 + sc);
            gload_lds16(Bb + (size_t)r * 1024 + kt * 64 + sc, Bs + r * 64 + sc);
        }
        __syncthreads();
        for (int kk = 0; kk < 2; ++kk) {
            bf16x8 af[4], bfr[4];
            for (int i = 0; i < 4; ++i)
                af[i] = *(const bf16x8*)(As + (wm + i * 16 + l15) * 64 + kk * 32 + quad * 8);
            for (int j = 0; j < 4; ++j)
                bfr[j] = *(const bf16x8*)(Bs + (wn + j * 16 + l15) * 64 + kk * 32 + quad * 8);
            for (int i = 0; i < 4; ++i)
                for (int j = 0; j < 4; ++j)
                    acc[i][j] = __builtin_amdgcn_mfma_f32_16x16x32_bf16(af[i], bfr[j],
                                                                        acc[i][j], 0, 0, 0);
        }
    }
    size_t cbase = ((size_t)s << 20) + (size_t)mt * 128 * 1024 + (size_t)nt * 128;
    for (int i = 0; i < 4; ++i)
        for (int j = 0; j < 4; ++j) {
            int m = wm + i * 16 + quad * 4;
            int n = wn + j * 16 + l15;
            for (int r = 0; r < 4; ++r) {
                float v = acc[i][j][r];
                if (F32OUT)
                    ((float*)Cout)[cbase + (size_t)(m + r) * 1024 + n] = v;
                else
                    ((bf16*)Cout)[cbase + (size_t)(m + r) * 1024 + n] = (bf16)v;
            }
        }
}

// ---------------- conv(1x3 along w) + bias, RoPE, emit fragment-layout Q/V ----
// in : Yb[s][h][w] bf16.
// out: Vhat[s][head][vrow(128)][d(128)][8w]: KEY-PERMUTED V rows. Within each
//      16-key group g (vrows 2g, 2g+1), slot (h,j) holds key 16g+4h+(j&3)+8(j>>2)
//      — exactly the 32x32 MFMA C-layout key order, so attention's P A-frags
//      are the exp'd S^T C-registers with NO cross-lane shuffle.
//      Qhat[s][head][dchunk(16)][w(1024)][8d]  (roped Q=K, frag layout, PRE-SCALED
//      by sqrt(log2(e)/32) so attention exp is a bare exp2)
__global__ void __launch_bounds__(256) conv_rope_kernel(
    const bf16* __restrict__ Yb, const float* __restrict__ wconv,
    const float* __restrict__ bconv, bf16* __restrict__ Qhat,
    bf16* __restrict__ Vhat, const float2* __restrict__ rtab) {
    __shared__ float Pt[32][260];
    const int s = blockIdx.z, cch = s & 3;
    const int h0 = blockIdx.y * 32, w0 = blockIdx.x * 256;
    const bf16* Y = Yb + ((size_t)s << 20);
    const float k0 = wconv[cch * 3], k1 = wconv[cch * 3 + 1], k2 = wconv[cch * 3 + 2];
    const float bias = bconv[cch];
    const float SQS = 0.21233045f;   // sqrt(log2(e)/32)

    // phase 1: conv 8 consecutive w per thread (4 iters cover 32h x 256w tile)
    for (int it = 0; it < 4; ++it) {
        const int hh = threadIdx.x >> 3;
        const int wseg = (threadIdx.x & 7) + it * 8;   // 0..31
        const int h = h0 + hh, w = w0 + wseg * 8;
        const bf16* yrow = Y + ((size_t)h << 10);
        bf16x8 yv = *(const bf16x8*)(yrow + w);
        float yc[10];
        yc[0] = (w > 0) ? (float)yrow[w - 1] : 0.f;
        for (int i = 0; i < 8; ++i) yc[i + 1] = (float)yv[i];
        yc[9] = (w + 8 < 1024) ? (float)yrow[w + 8] : 0.f;
        bf16x8 pb;
        for (int i = 0; i < 8; ++i) {
            float p = fmaf(k0, yc[i], fmaf(k1, yc[i + 1], fmaf(k2, yc[i + 2], bias)));
            Pt[hh][wseg * 8 + i] = p;
            pb[i] = (bf16)p;
        }
        const int head = h >> 7, d = h & 127;
        // permuted V store: keys w..w+3 -> vrow 2g (h=0), keys w+4..w+7 -> vrow 2g+1;
        // column base j0 = 4*((w>>3)&1) (keys 8..15 of the group land in slots 4..7)
        size_t vb = ((((size_t)s * 8 + head) * 128 + (w >> 4) * 2) << 10) + d * 8 +
                    ((w >> 3) & 1) * 4;
        bf16x4 lo = {pb[0], pb[1], pb[2], pb[3]};
        bf16x4 hi = {pb[4], pb[5], pb[6], pb[7]};
        *(bf16x4*)(Vhat + vb) = lo;
        *(bf16x4*)(Vhat + vb + 1024) = hi;
    }
    __syncthreads();
    // phase 2: rope 8 consecutive d per thread at fixed w, write Qhat (scaled)
    {
        const int dcb = threadIdx.x >> 6;            // 0..3 (dchunk within tile)
        const int head = h0 >> 7;
        const int d0 = (h0 & 127) + dcb * 8;         // global d of chunk start
        const int hb0 = dcb * 8;
        for (int it = 0; it < 4; ++it) {
            const int wl = (threadIdx.x & 63) + it * 64;
            const int w = w0 + wl;
            float q[8];
            if (d0 < 64) {
                for (int j = 0; j < 8; j += 2) {
                    float2 cs = rtab[(w << 5) + ((d0 + j) >> 1)];
                    float a = Pt[hb0 + j][wl], b = Pt[hb0 + j + 1][wl];
                    q[j]     = fmaf(a, cs.x, -b * cs.y);
                    q[j + 1] = fmaf(b, cs.x,  a * cs.y);
                }
            } else {
                for (int j = 0; j < 8; ++j) q[j] = Pt[hb0 + j][wl];
            }
            bf16x8 qb;
            for (int j = 0; j < 8; ++j) qb[j] = (bf16)(q[j] * SQS);
            *(bf16x8*)(Qhat + ((((size_t)s * 8 + head) * 16 + (d0 >> 3)) << 13) +
                       (size_t)w * 8) = qb;
        }
    }
}

// ---------------- fused flash attention: 32x32x16 MFMA, shuffle-free P --------
// grid 512 flat: sh = b&63, qtile = b>>6. 2 blocks/CU, 4 waves, 32 q/wave.
// S^T = K(A,m=key) x Q(B,n=q). V rows are key-permuted to the C-layout order,
// so P A-frags = exp'd C regs packed in place (no shfl, no LDS round-trip).
__global__ void __launch_bounds__(256, 2) attn_kernel(const bf16* __restrict__ Qhat,
                                                      const bf16* __restrict__ Vhat,
                                                      bf16* __restrict__ AO) {
    __shared__ alignas(16) char smem[66048];
    // buffers: buf b at smem + b*32768: Ks [16dc][64key][8] 16KB + Vs [8vrow][128d][8] 16KB
    // lsf at smem + 65536: 4 waves x 32 floats
    const int tid = threadIdx.x, lane = tid & 63, wave = tid >> 6;
    const int l31 = lane & 31, h = lane >> 5;
    const int b = blockIdx.x;
    const int sh = b & 63, qtile = b >> 6;
    const int s = sh >> 3, head = sh & 7, q0 = qtile * 128;
    const bf16* Qg = Qhat + (size_t)sh * 131072;
    const bf16* Vg = Vhat + (size_t)sh * 131072;

    // Q B-frags straight from global: n=q (lane&31), k=d: dc = kstep*2 + h
    const int myq = q0 + wave * 32 + l31;
    bf16x8 qf[8];
    for (int ks8 = 0; ks8 < 8; ++ks8)
        qf[ks8] = *(const bf16x8*)(Qg + (size_t)(ks8 * 2 + h) * 8192 + (size_t)myq * 8);

    f32x16 Oacc[4];
    for (int nt = 0; nt < 4; ++nt)
        for (int e = 0; e < 16; ++e) Oacc[nt][e] = 0.f;
    float lsum = 0.f;

    auto stage = [&](int kt, int buf) {
        bf16* Ks = (bf16*)(smem + buf * 32768);
        bf16* Vs = Ks + 8192;
        for (int t = 0; t < 4; ++t) {
            int dc = wave * 4 + t;
            gload_lds16(Qg + (size_t)dc * 8192 + (size_t)(kt * 64 + lane) * 8,
                        Ks + (dc * 64 + lane) * 8);
            int wc = dc >> 1, half = dc & 1;
            gload_lds16(Vg + (size_t)(kt * 8 + wc) * 1024 + (size_t)(half * 64 + lane) * 8,
                        Vs + (wc * 128 + half * 64 + lane) * 8);
        }
    };

    stage(0, 0);
    for (int kt = 0; kt < 16; ++kt) {
        __syncthreads();                  // drains prefetch vmcnt + prev-iter reads
        if (kt < 15) stage(kt + 1, (kt + 1) & 1);
        bf16* Ks = (bf16*)(smem + (kt & 1) * 32768);
        bf16* Vs = Ks + 8192;

        // ---- S^T = K * Q : m-tiles key {0..31},{32..63}; k = d in 8 steps of 16
        f32x16 st[2];
        for (int e = 0; e < 16; ++e) { st[0][e] = 0.f; st[1][e] = 0.f; }
        for (int ks8 = 0; ks8 < 8; ++ks8) {
            bf16x8 kf0 = *(const bf16x8*)(Ks + ((ks8 * 2 + h) * 64 + l31) * 8);
            bf16x8 kf1 = *(const bf16x8*)(Ks + ((ks8 * 2 + h) * 64 + 32 + l31) * 8);
            st[0] = __builtin_amdgcn_mfma_f32_32x32x16_bf16(kf0, qf[ks8], st[0], 0, 0, 0);
            st[1] = __builtin_amdgcn_mfma_f32_32x32x16_bf16(kf1, qf[ks8], st[1], 0, 0, 0);
        }

        // ---- exp all 32 regs in place -> P A-frags (V is key-permuted) ----
        bf16x8 pfr[4];                     // pfr[ks], ks = mt*2 + hh, regs e=hh*8+j
        float lacc = 0.f;
        for (int mt = 0; mt < 2; ++mt)
            for (int hh = 0; hh < 2; ++hh) {
                bf16x8 pf;
                for (int e = 0; e < 8; e += 2) {
                    float a = exp2f(st[mt][hh * 8 + e]);
                    float c = exp2f(st[mt][hh * 8 + e + 1]);
                    lacc += a + c;
                    pf[e] = (bf16)a;
                    pf[e + 1] = (bf16)c;
                }
                pfr[mt * 2 + hh] = pf;
            }
        lsum += lacc;

        // ---- O += P * V : k = key in 4 steps of 16 (permuted order on both sides)
        for (int ks = 0; ks < 4; ++ks) {
            const bf16x8 pf = pfr[ks];
            for (int nt = 0; nt < 4; ++nt) {
                bf16x8 vf = *(const bf16x8*)(Vs + ((ks * 2 + h) * 128 + nt * 32 + l31) * 8);
                Oacc[nt] = __builtin_amdgcn_mfma_f32_32x32x16_bf16(pf, vf, Oacc[nt], 0, 0, 0);
            }
        }
    }

    // ---- rinv broadcast: lsum per-lane (q=l31), halves hold key-halves ----
    lsum += __shfl_xor(lsum, 32);
    float* lsf = (float*)(smem + 65536) + wave * 32;
    if (lane < 32) lsf[lane] = 1.0f / lsum;
    f32x4 rv[4];
    __builtin_amdgcn_s_waitcnt(0);        // own LDS write visible (wave-private slot)
    for (int rg = 0; rg < 4; ++rg)
        rv[rg] = *(const f32x4*)(lsf + 8 * rg + 4 * h);

    // ---- epilogue: normalize, transpose through LDS, coalesced store ----
    __syncthreads();
    bf16* Ot = (bf16*)smem;               // [d(128)][q(128)] stride 136
    for (int nt = 0; nt < 4; ++nt) {
        int d = nt * 32 + l31;
        for (int rg = 0; rg < 4; ++rg) {
            int q = wave * 32 + 8 * rg + 4 * h;
            bf16x4 o4;
            for (int e = 0; e < 4; ++e)
                o4[e] = (bf16)(Oacc[nt][rg * 4 + e] * rv[rg][e]);
            *(bf16x4*)(Ot + d * 136 + q) = o4;
        }
    }
    __syncthreads();
    bf16* AOg = AO + ((size_t)s << 20);
    for (int it = 0; it < 8; ++it) {
        int d = it * 16 + (tid >> 4);
        int qc = (tid & 15) * 8;
        bf16x8 v = *(const bf16x8*)(Ot + d * 136 + qc);
        *(bf16x8*)(AOg + (size_t)(head * 128 + d) * 1024 + q0 + qc) = v;
    }
}

// ---------------- launch ----------------
extern "C" void kernel_launch(void* const* d_in, const int* in_sizes, int n_in,
                              void* d_out, int out_size, void* d_ws, size_t ws_size,
                              hipStream_t stream) {
    const float* x  = (const float*)d_in[0];
    const float* wq = (const float*)d_in[1];
    const float* wc = (const float*)d_in[2];
    const float* bc = (const float*)d_in[3];
    const float* wo = (const float*)d_in[4];
    float* out = (float*)d_out;

    char* ws = (char*)d_ws;
    bf16* xb   = (bf16*)ws;                      // 16 MiB (x bf16; later aliased as AO)
    bf16* wqb  = (bf16*)(ws + (16u << 20));      //  8 MiB
    bf16* wob  = (bf16*)(ws + (24u << 20));      //  8 MiB
    bf16* Yb   = (bf16*)(ws + (32u << 20));      // 16 MiB  proj output
    bf16* Qhat = (bf16*)(ws + (48u << 20));      // 16 MiB  roped Q=K, frag layout
    bf16* Vhat = (bf16*)(ws + (64u << 20));      // 16 MiB  V, key-permuted frag layout
    float2* rtab = (float2*)(ws + (80u << 20));  // 256 KiB cos/sin table
    bf16* AO   = xb;                             // alias: x consumed after gemm1

    cvt3_kernel<<<16384, 256, 0, stream>>>(x, xb, 2097152, wq, wqb, 1048576,
                                           wo, wob, 1048576);
    rope_tab_kernel<<<128, 256, 0, stream>>>(rtab);

    gemm_bt<false><<<512, 256, 0, stream>>>(xb, wqb, Yb);
    conv_rope_kernel<<<dim3(4, 32, 8), 256, 0, stream>>>(Yb, wc, bc, Qhat, Vhat, rtab);
    attn_kernel<<<512, 256, 0, stream>>>(Qhat, Vhat, AO);
    gemm_bt<true><<<512, 256, 0, stream>>>(AO, wob, out);
}